// Round 6
// baseline (189.557 us; speedup 1.0000x reference)
//
#include <hip/hip_runtime.h>
#include <cfloat>
#include <cmath>

#define MEM_DIM 2000
#define FEA     256
#define LAMBDA  0.0025f
#define HS_EPS  1e-12f

typedef unsigned short u16;
typedef _Float16 f16x8  __attribute__((ext_vector_type(8)));
typedef float    f32x16 __attribute__((ext_vector_type(16)));

static const int Y_ELEMS = 16 * 256 * 1024;   // y output elements

// workspace layout (float offsets): wsp u16[2][2048][256] = 2 MB at 0
#define WS_ZP 524288     // [16][16384] partial sum(e^z) per m-tile (1 MB)
// xs (f16 split of x, 16.8 MB) lives in the y output region (free until k_pvf).

// ---------------------------------------------------------------------------
// Kernel A: split x [16][256][1024] f32 -> xs planes [2][16][1024][256] f16
// ---------------------------------------------------------------------------
__global__ __launch_bounds__(256) void k_split_x(const float* __restrict__ x,
                                                 u16* __restrict__ xs) {
    __shared__ float tl[32][33];
    const int blk = blockIdx.x;           // 4096 = 16 b * 8 ct * 32 ht
    const int b   = blk >> 8;
    const int ct  = (blk >> 5) & 7;
    const int ht  = blk & 31;
    const int tx  = threadIdx.x & 31, ty = threadIdx.x >> 5;
#pragma unroll
    for (int i = 0; i < 4; ++i)
        tl[ty + 8 * i][tx] =
            x[(((b << 8) + (ct << 5) + ty + (i << 3)) << 10) + (ht << 5) + tx];
    __syncthreads();
#pragma unroll
    for (int i = 0; i < 4; ++i) {
        float v = tl[tx][ty + 8 * i];
        _Float16 a  = (_Float16)v;
        _Float16 bq = (_Float16)((v - (float)a) * 256.0f);
        const int hw = (ht << 5) + ty + (i << 3);
        const int c  = (ct << 5) + tx;
        const size_t o = (((size_t)(b << 10) + hw) << 8) + c;
        xs[o]           = *(u16*)&a;
        xs[4194304 + o] = *(u16*)&bq;
    }
}

// ---------------------------------------------------------------------------
// Kernel B: split W [2000][256] f32 -> wsp [2][2048][256] f16 (m zero-padded)
// ---------------------------------------------------------------------------
__global__ __launch_bounds__(256) void k_split_w(const float* __restrict__ W,
                                                 u16* __restrict__ wsp) {
    const int m = blockIdx.x;             // 2048
    const int c = threadIdx.x;
    float v = (m < MEM_DIM) ? W[(m << 8) + c] : 0.f;
    _Float16 a  = (_Float16)v;
    _Float16 bq = (_Float16)((v - (float)a) * 256.0f);
    wsp[(m << 8) + c]          = *(u16*)&a;
    wsp[524288 + (m << 8) + c] = *(u16*)&bq;
}

// ---------------------------------------------------------------------------
// Kernel 1: z = x.W^T via mfma_f32_32x32x16_f16, 2-split (3 passes, dual acc).
// Block: 128 rows x 128 m, BK=32, 4 waves (2x2), wave tile 64x64.
// LDS 48 KB: double-buffered {A0,A1,B0} tiles, each [128][32] f16.
// B1 (W residual) comes straight from global (L2-hot) into register
// fragments, prefetched one K-tile ahead -> frees 16 KB -> 3 blocks/CU.
// MFMA values and instruction order unchanged vs round 5 -> E bit-identical.
// ---------------------------------------------------------------------------
__global__ __launch_bounds__(256) void k_scores_mfma(
    const u16* __restrict__ xs, const u16* __restrict__ wsp,
    float* __restrict__ S, float* __restrict__ zp) {
    __shared__ u16 lds[24576];   // 48 KB = 2 x 24 KB buffers
    const int t    = threadIdx.x;
    const int lane = t & 63;
    const int w    = t >> 6;
    const int wr   = w >> 1, wc = w & 1;
    const int lr   = lane & 31, lg = lane >> 5;

    const int bx  = blockIdx.x;
    const int wg  = ((bx & 7) << 8) | (bx >> 3);   // XCD swizzle (2048 = 8*256)
    const int m0t = wg & 15;
    const int rt  = wg >> 4;
    const int m0  = m0t << 7;
    const int b   = rt >> 3;
    const int hw0 = (rt & 7) << 7;

    // staging: 6 issues x 256 thr x 16 B = 24 KB/buffer. slot s -> tile(s>>9)
    // in {A0,A1,B0}; row r=(s&511)>>2, phys chunk cp=s&3 holds logical
    // chunk cp^((r>>1)&3).
    const u16* gsrc[6];
#pragma unroll
    for (int i = 0; i < 6; ++i) {
        const int s = (i << 8) + t;
        const int tile = s >> 9;
        const int u = s & 511;
        const int r = u >> 2;
        const int cl = (u & 3) ^ ((r >> 1) & 3);
        if (tile < 2)
            gsrc[i] = xs + tile * 4194304 + (((b << 10) + hw0 + r) << 8) + (cl << 3);
        else
            gsrc[i] = wsp + ((m0 + r) << 8) + (cl << 3);
    }

    f32x16 acc1[2][2], acc2[2][2];
#pragma unroll
    for (int i = 0; i < 2; ++i)
#pragma unroll
        for (int j = 0; j < 2; ++j)
#pragma unroll
            for (int e = 0; e < 16; ++e) { acc1[i][j][e] = 0.f; acc2[i][j][e] = 0.f; }

    #define STAGE(kt, bufb)                                                          \
        {                                                                            \
            _Pragma("unroll")                                                        \
            for (int i = 0; i < 6; ++i) {                                            \
                const int s = (i << 8) + t;                                          \
                __builtin_amdgcn_global_load_lds(                                    \
                    (const __attribute__((address_space(1))) unsigned int*)(gsrc[i] + ((kt) << 5)), \
                    (__attribute__((address_space(3))) unsigned int*)&lds[(bufb) + (s << 3)],       \
                    16, 0, 0);                                                       \
            }                                                                        \
        }

    // b1 (W residual) register fragments, one K-tile lookahead
    f16x8 b1c[2][2], b1n[2][2];
    #define LOADB1(dst, kt)                                                          \
        {                                                                            \
            _Pragma("unroll")                                                        \
            for (int mi = 0; mi < 2; ++mi)                                           \
                _Pragma("unroll")                                                    \
                for (int ks = 0; ks < 2; ++ks)                                       \
                    dst[mi][ks] = *(const f16x8*)&wsp[524288 +                       \
                        ((m0 + (wc << 6) + (mi << 5) + lr) << 8) + ((kt) << 5) +     \
                        (((ks << 1) + lg) << 3)];                                    \
        }

    #define COMPUTE(bufb)                                                            \
        {                                                                            \
            _Pragma("unroll")                                                        \
            for (int ks = 0; ks < 2; ++ks) {                                         \
                f16x8 a0[2], a1[2], b0[2];                                           \
                _Pragma("unroll")                                                    \
                for (int ri = 0; ri < 2; ++ri) {                                     \
                    const int R  = (wr << 6) + (ri << 5) + lr;                       \
                    const int pc = ((ks << 1) + lg) ^ ((R >> 1) & 3);                \
                    a0[ri] = *(const f16x8*)&lds[(bufb) +        (R << 5) + (pc << 3)]; \
                    a1[ri] = *(const f16x8*)&lds[(bufb) + 4096 + (R << 5) + (pc << 3)]; \
                }                                                                    \
                _Pragma("unroll")                                                    \
                for (int mi = 0; mi < 2; ++mi) {                                     \
                    const int M  = (wc << 6) + (mi << 5) + lr;                       \
                    const int pc = ((ks << 1) + lg) ^ ((M >> 1) & 3);                \
                    b0[mi] = *(const f16x8*)&lds[(bufb) + 8192 + (M << 5) + (pc << 3)]; \
                }                                                                    \
                _Pragma("unroll")                                                    \
                for (int ri = 0; ri < 2; ++ri)                                       \
                    _Pragma("unroll")                                                \
                    for (int mi = 0; mi < 2; ++mi) {                                 \
                        acc2[ri][mi] = __builtin_amdgcn_mfma_f32_32x32x16_f16(a0[ri], b1c[mi][ks], acc2[ri][mi], 0, 0, 0); \
                        acc2[ri][mi] = __builtin_amdgcn_mfma_f32_32x32x16_f16(a1[ri], b0[mi],      acc2[ri][mi], 0, 0, 0); \
                        acc1[ri][mi] = __builtin_amdgcn_mfma_f32_32x32x16_f16(a0[ri], b0[mi],      acc1[ri][mi], 0, 0, 0); \
                    }                                                                \
            }                                                                        \
        }

    STAGE(0, 0);
    LOADB1(b1c, 0);
    __syncthreads();
#pragma unroll
    for (int kt = 0; kt < 8; ++kt) {
        if (kt < 7) {
            STAGE(kt + 1, ((kt + 1) & 1) * 12288);   // prefetch next K-tile
            LOADB1(b1n, kt + 1);
        }
        COMPUTE((kt & 1) * 12288);
        __syncthreads();
#pragma unroll
        for (int mi = 0; mi < 2; ++mi)
#pragma unroll
            for (int ks = 0; ks < 2; ++ks) b1c[mi][ks] = b1n[mi][ks];
    }
    #undef STAGE
    #undef LOADB1
    #undef COMPUTE

    float* zf = (float*)lds;

    float rs[2][16];
#pragma unroll
    for (int ri = 0; ri < 2; ++ri)
#pragma unroll
        for (int q = 0; q < 16; ++q) rs[ri][q] = 0.f;

#pragma unroll
    for (int ri = 0; ri < 2; ++ri)
#pragma unroll
        for (int mi = 0; mi < 2; ++mi) {
            const int m = m0 + (wc << 6) + (mi << 5) + lr;
            const bool valid = (m < MEM_DIM);
            float e[16];
#pragma unroll
            for (int q = 0; q < 16; ++q) {
                float z = acc1[ri][mi][q] + acc2[ri][mi][q] * 0.00390625f;
                e[q] = valid ? expf(z) : 0.f;
                rs[ri][q] += e[q];
            }
            if (valid) {
                const size_t pb = ((size_t)(b * MEM_DIM + m) << 10) + hw0
                                + (wr << 6) + (ri << 5) + (lg << 2);
#pragma unroll
                for (int q4 = 0; q4 < 4; ++q4) {
                    float4 v = {e[4 * q4], e[4 * q4 + 1], e[4 * q4 + 2], e[4 * q4 + 3]};
                    *(float4*)&S[pb + (q4 << 3)] = v;
                }
            }
        }

#pragma unroll
    for (int ri = 0; ri < 2; ++ri)
#pragma unroll
        for (int q = 0; q < 16; ++q) {
            float v = rs[ri][q];
            v += __shfl_xor(v, 1);
            v += __shfl_xor(v, 2);
            v += __shfl_xor(v, 4);
            v += __shfl_xor(v, 8);
            v += __shfl_xor(v, 16);
            rs[ri][q] = v;
        }
    if (lr == 0) {
#pragma unroll
        for (int ri = 0; ri < 2; ++ri)
#pragma unroll
            for (int q = 0; q < 16; ++q) {
                const int row = (wr << 6) + (ri << 5) + (q & 3) + ((q >> 2) << 3) + (lg << 2);
                zf[(wc << 7) + row] = rs[ri][q];
            }
    }
    __syncthreads();
    if (t < 128)
        zp[m0t * 16384 + (b << 10) + hw0 + t] = zf[t] + zf[128 + t];
}

// ---------------------------------------------------------------------------
// Kernel 2: fused D-reduce + shrink + normalize + sparse PV, E in registers.
// Block = 16 rows x full m range (8 waves, 512 thr); grid 1024.
// Each thread holds its 63 E-values in registers (fully unrolled, static
// indices): pass A computes D, block-reduce, pass B writes final att and
// ballot-accumulates y. E is read from HBM/L3 exactly once.
// ---------------------------------------------------------------------------
__global__ __launch_bounds__(512) void k_pvf(float* __restrict__ att,
                                             const float* __restrict__ W,
                                             float* __restrict__ y,
                                             const float* __restrict__ zp) {
    __shared__ float ylds[16][257];
    __shared__ float dred[32][16];
    const int t    = threadIdx.x;
    const int blk  = blockIdx.x;          // 1024 = 16 b x 64 row-chunks(16)
    const int b    = blk >> 6;
    const int hw0  = (blk & 63) << 4;
    const int lane = t & 63, wv = t >> 6;
    const int srow = lane & 15;           // row within chunk
    const int smq  = lane >> 4;           // m offset 0..3
    const int row  = (b << 10) + hw0 + srow;

    for (int i = t; i < 16 * 257; i += 512) ((float*)ylds)[i] = 0.f;

    float Z = 0.f;
#pragma unroll
    for (int mt = 0; mt < 16; ++mt) Z += zp[mt * 16384 + row];
    const float rZ = 1.f / Z;

    const size_t base = ((size_t)(b * MEM_DIM) << 10) + hw0 + srow;
    const int mb = (wv << 2) + smq;       // 0..31

    // ---- load all E into registers (one HBM/L3 read) ----
    float e[63];
#pragma unroll
    for (int j = 0; j < 63; ++j) {
        const int m = (j << 5) + mb;
        e[j] = (m < MEM_DIM) ? att[base + ((size_t)m << 10)] : 0.f;
    }

    // ---- pass A: D from registers ----
    float D = 0.f;
#pragma unroll
    for (int j = 0; j < 63; ++j) {
        float a = e[j] * rZ;
        float d = a - LAMBDA;
        D += fmaxf(d, 0.f) * a / (fabsf(d) + HS_EPS);
    }
    dred[mb][srow] = D;
    __syncthreads();
    float Dv = 0.f;
#pragma unroll
    for (int i = 0; i < 32; ++i) Dv += dred[i][srow];
    const float rD = 1.f / fmaxf(Dv, HS_EPS);

    // ---- pass B: write final att, ballot-accumulate y ----
#pragma unroll
    for (int j = 0; j < 63; ++j) {
        const int m = (j << 5) + mb;
        float a = e[j] * rZ;
        float d = a - LAMBDA;
        float s = fmaxf(d, 0.f) * a / (fabsf(d) + HS_EPS);
        float v = s * rD;
        if (m < MEM_DIM) att[base + ((size_t)m << 10)] = v;
        unsigned long long msk = __ballot(v != 0.f);
        while (msk) {
            int src = __ffsll(msk) - 1;
            msk &= msk - 1;
            float vv = __shfl(v, src);
            const int ms  = (j << 5) + (wv << 2) + (src >> 4);
            const int rs_ = src & 15;
            float w0 = W[ms * FEA + lane];
            float w1 = W[ms * FEA + 64 + lane];
            float w2 = W[ms * FEA + 128 + lane];
            float w3 = W[ms * FEA + 192 + lane];
            float* yp = &ylds[rs_][0];
            atomicAdd(&yp[lane],       vv * w0);
            atomicAdd(&yp[64 + lane],  vv * w1);
            atomicAdd(&yp[128 + lane], vv * w2);
            atomicAdd(&yp[192 + lane], vv * w3);
        }
    }
    __syncthreads();

    // write y: 16 rows x 256 c
    for (int i = t; i < 4096; i += 512) {
        const int r = i & 15;
        const int c = i >> 4;
        y[(((b << 8) + c) << 10) + hw0 + r] = ylds[r][c];
    }
}

// ---------------------------------------------------------------------------
extern "C" void kernel_launch(void* const* d_in, const int* in_sizes, int n_in,
                              void* d_out, int out_size, void* d_ws, size_t ws_size,
                              hipStream_t stream) {
    const float* x = (const float*)d_in[0];
    const float* W = (const float*)d_in[1];
    float* out = (float*)d_out;
    float* y   = out;
    float* att = out + (size_t)Y_ELEMS;
    float* wsf = (float*)d_ws;
    u16*   wsp = (u16*)d_ws;                 // 2 MB
    float* zp  = wsf + WS_ZP;
    u16*   xs  = (u16*)y;                    // 16.8 MB staging in y region
                                             // (consumed before k_pvf writes y)

    k_split_x    <<<4096, 256, 0, stream>>>(x, xs);
    k_split_w    <<<2048, 256, 0, stream>>>(W, wsp);
    k_scores_mfma<<<2048, 256, 0, stream>>>(xs, wsp, att, zp);
    k_pvf        <<<1024, 512, 0, stream>>>(att, W, y, zp);
}